// Round 13
// baseline (76.481 us; speedup 1.0000x reference)
//
#include <hip/hip_runtime.h>
#include <hip/hip_bf16.h>
#include <math.h>

#define KS 3
#define C_IN 64
#define F_OUT 128
#define NPOS 9
#define HH 128
#define WWID 128
#define NB 16

typedef __attribute__((ext_vector_type(8))) short bf16x8;
typedef __attribute__((ext_vector_type(4))) float f32x4;

__device__ __forceinline__ unsigned short f2bf(float f) {
  union { float f; unsigned u; } v; v.f = f;
  unsigned u = v.u;
  return (unsigned short)((u + 0x7FFFu + ((u >> 16) & 1u)) >> 16);  // RNE
}
__device__ __forceinline__ unsigned cvtpk(float lo, float hi) {
  unsigned r;
  asm("v_cvt_pk_bf16_f32 %0, %1, %2" : "=v"(r) : "v"(lo), "v"(hi));
  return r;
}
__device__ __forceinline__ bf16x8 pack8(float4 v0, float4 v1) {
  union { unsigned u[4]; bf16x8 v; } r;
  r.u[0] = cvtpk(v0.x, v0.y); r.u[1] = cvtpk(v0.z, v0.w);
  r.u[2] = cvtpk(v1.x, v1.y); r.u[3] = cvtpk(v1.z, v1.w);
  return r.v;
}
__device__ __forceinline__ void gload16(const void* g, void* l) {
  __builtin_amdgcn_global_load_lds(
      (const __attribute__((address_space(1))) unsigned int*)g,
      (__attribute__((address_space(3))) unsigned int*)l, 16, 0, 0);
}

// ---- Kernel 1: AW (bf16 in {-1,0,1}) sliced by kernel-row i (= p/3):
// slice s = positions 3s..3s+2, all 128 f, all 64 ch (48 KiB each), LINEAR.
// elem off = s*24576 + ((pl*128+f)*8 + (g^(f&7)))*8 + (c&7).  (r10-verified)
__global__ void compute_aw(const float* __restrict__ kern,
                           const float* __restrict__ D,
                           const float* __restrict__ gu,
                           unsigned short* __restrict__ AWsw) {
  int t = blockIdx.x * blockDim.x + threadIdx.x;
  if (t >= F_OUT * C_IN) return;
  int base = t * NPOS;
  float pert[NPOS];
#pragma unroll
  for (int n = 0; n < NPOS; ++n) {
    float u = gu[base + n];
    float g = -0.001f * logf(-logf(u + 1e-20f) + 1e-20f);
    pert[n] = D[base + n] + g;
  }
  unsigned mask = 0;
#pragma unroll
  for (int k = 0; k < 4; ++k) {
    int best = 0; float bv = -INFINITY;
#pragma unroll
    for (int n = 0; n < NPOS; ++n) {
      bool taken = (mask >> n) & 1;
      if (!taken && pert[n] > bv) { bv = pert[n]; best = n; }
    }
    mask |= (1u << best);
  }
#pragma unroll
  for (int n = 0; n < NPOS; ++n) {
    int L = base + n;
    float kv = kern[L];
    float sg = (kv > 0.f) ? 1.f : ((kv < 0.f) ? -1.f : 0.f);
    float v = ((mask >> n) & 1) ? sg : 0.f;
    int f = L & (F_OUT - 1);
    int r = L >> 7;
    int c = r & (C_IN - 1);
    int p = r >> 6;
    int s = p / 3, pl = p % 3;
    int g = c >> 3;
    int off = s * 24576 + ((pl * F_OUT + f) * 8 + (g ^ (f & 7))) * 8 + (c & 7);
    AWsw[off] = f2bf(v);
  }
}

// ---- Kernel 2: r11's conv6 + T14 A-split. 1024 thr / 16 waves, 1 block/CU,
// wave tile 64x64 (4 waves/SIMD). A-prologue stages rows 0-3 only; rows 4/5
// are issued as global loads before phases 0/1 and drained (cvt+swizzled
// ds_write) inside the existing BWRITE barrier windows. B0 gload_lds issued
// first so its drain hides under memset+prologue.
__global__ __launch_bounds__(1024, 4)
void conv6b(const float* __restrict__ x,
            const unsigned short* __restrict__ AWsw,
            const float* __restrict__ bias,
            float* __restrict__ out) {
  __shared__ __align__(16) unsigned short As[6 * 130 * 64];   // 99840 B
  __shared__ __align__(16) unsigned short Bs[3 * F_OUT * 64]; // 49152 B

  int tid = threadIdx.x;
  int lane = tid & 63, wave = tid >> 6;
  int lr = lane & 15, lg = lane >> 4;

  int bid = blockIdx.x;
  int wg = (bid & 7) * 64 + (bid >> 3);   // XCD-contiguous (512 % 8 == 0)
  int n = wg >> 5;
  int h0 = (wg & 31) * 4;

  int ro = wave >> 2;                 // output row within strip (0..3)
  int m0 = ((wave >> 1) & 1) * 64;    // px half
  int f0 = (wave & 1) * 64;           // f half

  const float* xim = x + ((long long)n * HH) * WWID * C_IN;

  // ---- B0 via gload_lds FIRST (48 wave-issues, 3/wave; drains at bar1,
  // hidden under memset + A-prologue VALU)
#pragma unroll
  for (int k = 0; k < 3; ++k) {
    int wi = wave * 3 + k;
    gload16(AWsw + wi * 512 + lane * 8, (char*)Bs + wi * 1024);
  }

  // ---- memset: edge blocks zero all of As; interior only pp=0/129 pads.
  bf16x8 z = {};
  if (h0 == 0 || h0 == 124) {
    for (int t = tid; t < 6240; t += 1024)
      *reinterpret_cast<bf16x8*>(As + t * 8) = z;
  } else if (tid < 96) {
    int r = tid >> 4, k = tid & 15;
    int pp = (k >> 3) ? 129 : 0, c8 = k & 7;
    *reinterpret_cast<bf16x8*>((char*)As + r * 16640 + pp * 128 +
                               ((c8 ^ (pp & 7)) << 4)) = z;
  }

  // ---- A-prologue: rows 0..3 (slots 0..3), 4096 chunks, 4/thread
#pragma unroll
  for (int t = 0; t < 4; ++t) {
    int cid = t * 1024 + tid;
    int r = cid >> 10, rem = cid & 1023;
    int px = rem >> 3, c8 = rem & 7;
    int hh = h0 - 1 + r;
    if ((unsigned)hh < (unsigned)HH) {
      const float* sp = xim + (long long)hh * (WWID * C_IN) + px * C_IN + c8 * 8;
      float4 v0 = *reinterpret_cast<const float4*>(sp);
      float4 v1 = *reinterpret_cast<const float4*>(sp + 4);
      int pp = px + 1;
      *reinterpret_cast<bf16x8*>((char*)As + r * 16640 + pp * 128 +
                                 ((c8 ^ (pp & 7)) << 4)) = pack8(v0, v1);
    }
  }
  __syncthreads();

  f32x4 acc[4][4] = {};
  bf16x8 pre[3];
  float4 xr0, xr1;               // parked next-row chunk (1 chunk/thread)
  int pxi = tid >> 3, c8i = tid & 7;   // this thread's (px, c8) for rows 4/5

#define PREFETCH(SN)                                                         \
  _Pragma("unroll")                                                          \
  for (int k = 0; k < 3; ++k)                                                \
    pre[k] = *reinterpret_cast<const bf16x8*>(                               \
        AWsw + (SN) * 24576 + (k * 1024 + tid) * 8);

#define BWRITE()                                                             \
  _Pragma("unroll")                                                          \
  for (int k = 0; k < 3; ++k)                                                \
    *reinterpret_cast<bf16x8*>(Bs + (k * 1024 + tid) * 8) = pre[k];

  // issue row R (slot R) loads: hh = h0-1+R (clamped; R=4 always valid)
#define ISSUE_ROW(R)                                                         \
  {                                                                          \
    int hh = h0 - 1 + (R);                                                   \
    int hc = hh > 127 ? 127 : hh;                                            \
    const float* sp = xim + (long long)hc * (WWID * C_IN) + pxi * C_IN +     \
                      c8i * 8;                                               \
    xr0 = *reinterpret_cast<const float4*>(sp);                              \
    xr1 = *reinterpret_cast<const float4*>(sp + 4);                          \
  }

#define DRAIN_ROW(R)                                                         \
  {                                                                          \
    int hh = h0 - 1 + (R);                                                   \
    bf16x8 val = (hh < HH) ? pack8(xr0, xr1) : z;                            \
    int pp = pxi + 1;                                                        \
    *reinterpret_cast<bf16x8*>((char*)As + (R) * 16640 + pp * 128 +          \
                               ((c8i ^ (pp & 7)) << 4)) = val;               \
  }

  // one slice-phase: 3 positions (j) x 2 ch x (4 b + 4 a reads + 16 MFMA)
#define COMPUTE(S)                                                           \
  __builtin_amdgcn_s_setprio(1);                                             \
  _Pragma("unroll")                                                          \
  for (int pl = 0; pl < 3; ++pl) {                                           \
    _Pragma("unroll")                                                        \
    for (int ch = 0; ch < 2; ++ch) {                                         \
      const char* bp = (const char*)Bs + pl * 16384 + (f0 << 7) + lr * 128 + \
                       (((ch * 4 + lg) ^ (lr & 7)) << 4);                    \
      bf16x8 b[4];                                                           \
      _Pragma("unroll")                                                      \
      for (int nf = 0; nf < 4; ++nf)                                         \
        b[nf] = *reinterpret_cast<const bf16x8*>(bp + nf * 2048);            \
      bf16x8 a[4];                                                           \
      _Pragma("unroll")                                                      \
      for (int mfi = 0; mfi < 4; ++mfi) {                                    \
        int pxb = m0 + mfi * 16 + lr + pl;                                   \
        a[mfi] = *reinterpret_cast<const bf16x8*>(                           \
            (const char*)As + (ro + (S)) * 16640 + pxb * 128 +               \
            (((ch * 4 + lg) ^ (pxb & 7)) << 4));                             \
      }                                                                      \
      _Pragma("unroll")                                                      \
      for (int mfi = 0; mfi < 4; ++mfi)                                      \
        _Pragma("unroll")                                                    \
        for (int nf = 0; nf < 4; ++nf)                                       \
          acc[mfi][nf] = __builtin_amdgcn_mfma_f32_16x16x32_bf16(            \
              a[mfi], b[nf], acc[mfi][nf], 0, 0, 0);                         \
    }                                                                        \
  }                                                                          \
  __builtin_amdgcn_s_setprio(0);

  PREFETCH(1)
  ISSUE_ROW(4)                 // in flight across phase 0
  COMPUTE(0)                   // reads slots 0..3
  __syncthreads();
  BWRITE()
  DRAIN_ROW(4)                 // slot 4 ready for phase 1
  __syncthreads();
  PREFETCH(2)
  ISSUE_ROW(5)                 // in flight across phase 1
  COMPUTE(1)                   // reads slots 1..4
  __syncthreads();
  BWRITE()
  DRAIN_ROW(5)                 // slot 5 ready for phase 2
  __syncthreads();
  COMPUTE(2)                   // reads slots 2..5

  // ---- epilogue: f = f0+nf*16+lr, w = m0+mfi*16+lg*4+r4; nf-inner stores.
  float bi[4];
#pragma unroll
  for (int nf = 0; nf < 4; ++nf) bi[nf] = bias[f0 + nf * 16 + lr];
  int ho = h0 + ro;
  long long ob = ((long long)(n * HH + ho)) * WWID * F_OUT + f0 + lr;
#pragma unroll
  for (int mfi = 0; mfi < 4; ++mfi) {
#pragma unroll
    for (int r4 = 0; r4 < 4; ++r4) {
      int w = m0 + mfi * 16 + lg * 4 + r4;
      float* op = out + ob + (long long)w * F_OUT;
#pragma unroll
      for (int nf = 0; nf < 4; ++nf)
        op[nf * 16] = fmaxf(acc[mfi][nf][r4] + bi[nf], 0.f);
    }
  }
#undef PREFETCH
#undef BWRITE
#undef ISSUE_ROW
#undef DRAIN_ROW
#undef COMPUTE
}

extern "C" void kernel_launch(void* const* d_in, const int* in_sizes, int n_in,
                              void* d_out, int out_size, void* d_ws, size_t ws_size,
                              hipStream_t stream) {
  const float* x    = (const float*)d_in[0];  // (16,128,128,64)
  const float* kern = (const float*)d_in[1];  // (3,3,64,128)
  const float* bias = (const float*)d_in[2];  // (128,)
  const float* D    = (const float*)d_in[3];  // (3,3,64,128)
  const float* gu   = (const float*)d_in[4];  // (1,128,64,9)

  unsigned short* AWsw = (unsigned short*)d_ws;  // 3 x 48 KiB = 144 KiB

  compute_aw<<<(F_OUT * C_IN + 255) / 256, 256, 0, stream>>>(kern, D, gu, AWsw);

  conv6b<<<NB * (HH / 4), 1024, 0, stream>>>(x, AWsw, bias, (float*)d_out);
}

// Round 14
// 57.439 us; speedup vs baseline: 1.3315x; 1.3315x over previous
//
#include <hip/hip_runtime.h>
#include <hip/hip_bf16.h>
#include <math.h>

#define KS 3
#define C_IN 64
#define F_OUT 128
#define NPOS 9
#define HH 128
#define WWID 128
#define NB 16

typedef __attribute__((ext_vector_type(8))) short bf16x8;
typedef __attribute__((ext_vector_type(4))) float f32x4;

__device__ __forceinline__ unsigned short f2bf(float f) {
  union { float f; unsigned u; } v; v.f = f;
  unsigned u = v.u;
  return (unsigned short)((u + 0x7FFFu + ((u >> 16) & 1u)) >> 16);  // RNE
}
__device__ __forceinline__ unsigned cvtpk(float lo, float hi) {
  unsigned r;
  asm("v_cvt_pk_bf16_f32 %0, %1, %2" : "=v"(r) : "v"(lo), "v"(hi));
  return r;
}
__device__ __forceinline__ bf16x8 pack8(float4 v0, float4 v1) {
  union { unsigned u[4]; bf16x8 v; } r;
  r.u[0] = cvtpk(v0.x, v0.y); r.u[1] = cvtpk(v0.z, v0.w);
  r.u[2] = cvtpk(v1.x, v1.y); r.u[3] = cvtpk(v1.z, v1.w);
  return r.v;
}
__device__ __forceinline__ void gload16(const void* g, void* l) {
  __builtin_amdgcn_global_load_lds(
      (const __attribute__((address_space(1))) unsigned int*)g,
      (__attribute__((address_space(3))) unsigned int*)l, 16, 0, 0);
}

// ---- Kernel 1: AW (bf16 in {-1,0,1}) sliced by kernel-row i (= p/3):
// slice s holds positions 3s..3s+2, all 128 f, all 64 ch (48 KiB each).
// Element (p,f,c): pl=p%3, g=c>>3, slot=g^(f&7) ->
// elem off = s*24576 + ((pl*128+f)*8 + slot)*8 + (c&7).  (r10-verified)
__global__ void compute_aw(const float* __restrict__ kern,
                           const float* __restrict__ D,
                           const float* __restrict__ gu,
                           unsigned short* __restrict__ AWsw) {
  int t = blockIdx.x * blockDim.x + threadIdx.x;
  if (t >= F_OUT * C_IN) return;
  int base = t * NPOS;
  float pert[NPOS];
#pragma unroll
  for (int n = 0; n < NPOS; ++n) {
    float u = gu[base + n];
    float g = -0.001f * logf(-logf(u + 1e-20f) + 1e-20f);
    pert[n] = D[base + n] + g;
  }
  unsigned mask = 0;
#pragma unroll
  for (int k = 0; k < 4; ++k) {
    int best = 0; float bv = -INFINITY;
#pragma unroll
    for (int n = 0; n < NPOS; ++n) {
      bool taken = (mask >> n) & 1;
      if (!taken && pert[n] > bv) { bv = pert[n]; best = n; }
    }
    mask |= (1u << best);
  }
#pragma unroll
  for (int n = 0; n < NPOS; ++n) {
    int L = base + n;
    float kv = kern[L];
    float sg = (kv > 0.f) ? 1.f : ((kv < 0.f) ? -1.f : 0.f);
    float v = ((mask >> n) & 1) ? sg : 0.f;
    int f = L & (F_OUT - 1);
    int r = L >> 7;
    int c = r & (C_IN - 1);
    int p = r >> 6;
    int s = p / 3, pl = p % 3;
    int g = c >> 3;
    int slot = g ^ (f & 7);
    int off = s * 24576 + ((pl * F_OUT + f) * 8 + slot) * 8 + (c & 7);
    AWsw[off] = f2bf(v);
  }
}

// ---- Kernel 2: fused implicit-GEMM conv — r11's conv6 (best measured:
// 57.2 us total). 1024 thr / 16 waves, wave tile 64(M) x 64(N) (mf=4, nf=4,
// acc=64) -> 4 waves/SIMD. 3-phase B-slicing, 6 barriers, verified swizzles.
__global__ __launch_bounds__(1024, 4)
void conv6(const float* __restrict__ x,
           const unsigned short* __restrict__ AWsw,
           const float* __restrict__ bias,
           float* __restrict__ out) {
  __shared__ __align__(16) unsigned short As[6 * 130 * 64];   // 99840 B
  __shared__ __align__(16) unsigned short Bs[3 * F_OUT * 64]; // 49152 B

  int tid = threadIdx.x;
  int lane = tid & 63, wave = tid >> 6;
  int lr = lane & 15, lg = lane >> 4;

  int bid = blockIdx.x;
  int wg = (bid & 7) * 64 + (bid >> 3);   // XCD-contiguous (512 % 8 == 0)
  int n = wg >> 5;
  int h0 = (wg & 31) * 4;

  int ro = wave >> 2;                 // output row within strip (0..3)
  int m0 = ((wave >> 1) & 1) * 64;    // px half
  int f0 = (wave & 1) * 64;           // f half

  // ---- memset: edge blocks zero all of As; interior only pp=0/129 pads.
  bf16x8 z = {};
  if (h0 == 0 || h0 == 124) {
    for (int t = tid; t < 6240; t += 1024)
      *reinterpret_cast<bf16x8*>(As + t * 8) = z;
  } else if (tid < 96) {
    int r = tid >> 4, k = tid & 15;
    int pp = (k >> 3) ? 129 : 0, c8 = k & 7;
    *reinterpret_cast<bf16x8*>((char*)As + r * 16640 + pp * 128 +
                               ((c8 ^ (pp & 7)) << 4)) = z;
  }
  __syncthreads();

  // ---- B0 via gload_lds (48 wave-issues, 3/wave; drain hides under A-stage)
#pragma unroll
  for (int k = 0; k < 3; ++k) {
    int wi = wave * 3 + k;
    gload16(AWsw + wi * 512 + lane * 8, (char*)Bs + wi * 1024);
  }

  // ---- A-stage: 6144 chunks = (r 0..5) x (px 0..127) x (c8 0..7), 6/thread
  const float* xim = x + ((long long)n * HH) * WWID * C_IN;
#pragma unroll
  for (int t = 0; t < 6; ++t) {
    int cid = t * 1024 + tid;
    int r = cid >> 10, rem = cid & 1023;
    int px = rem >> 3, c8 = rem & 7;
    int hh = h0 - 1 + r;
    if ((unsigned)hh < (unsigned)HH) {
      const float* sp = xim + (long long)hh * (WWID * C_IN) + px * C_IN + c8 * 8;
      float4 v0 = *reinterpret_cast<const float4*>(sp);
      float4 v1 = *reinterpret_cast<const float4*>(sp + 4);
      int pp = px + 1;
      *reinterpret_cast<bf16x8*>((char*)As + r * 16640 + pp * 128 +
                                 ((c8 ^ (pp & 7)) << 4)) = pack8(v0, v1);
    }
  }
  __syncthreads();

  f32x4 acc[4][4] = {};
  bf16x8 pre[3];

#define PREFETCH(SN)                                                         \
  _Pragma("unroll")                                                          \
  for (int k = 0; k < 3; ++k)                                                \
    pre[k] = *reinterpret_cast<const bf16x8*>(                               \
        AWsw + (SN) * 24576 + (k * 1024 + tid) * 8);

#define BWRITE()                                                             \
  _Pragma("unroll")                                                          \
  for (int k = 0; k < 3; ++k)                                                \
    *reinterpret_cast<bf16x8*>(Bs + (k * 1024 + tid) * 8) = pre[k];

  // one slice-phase: 3 positions (j=pl) x 2 ch x (4 b + 4 a reads + 16 MFMA)
#define COMPUTE(S)                                                           \
  __builtin_amdgcn_s_setprio(1);                                             \
  _Pragma("unroll")                                                          \
  for (int pl = 0; pl < 3; ++pl) {                                           \
    _Pragma("unroll")                                                        \
    for (int ch = 0; ch < 2; ++ch) {                                         \
      const char* bp = (const char*)Bs + pl * 16384 + (f0 << 7) + lr * 128 + \
                       (((ch * 4 + lg) ^ (lr & 7)) << 4);                    \
      bf16x8 b[4];                                                           \
      _Pragma("unroll")                                                      \
      for (int nf = 0; nf < 4; ++nf)                                         \
        b[nf] = *reinterpret_cast<const bf16x8*>(bp + nf * 2048);            \
      bf16x8 a[4];                                                           \
      _Pragma("unroll")                                                      \
      for (int mfi = 0; mfi < 4; ++mfi) {                                    \
        int pxb = m0 + mfi * 16 + lr + pl;                                   \
        a[mfi] = *reinterpret_cast<const bf16x8*>(                           \
            (const char*)As + (ro + (S)) * 16640 + pxb * 128 +               \
            (((ch * 4 + lg) ^ (pxb & 7)) << 4));                             \
      }                                                                      \
      _Pragma("unroll")                                                      \
      for (int mfi = 0; mfi < 4; ++mfi)                                      \
        _Pragma("unroll")                                                    \
        for (int nf = 0; nf < 4; ++nf)                                       \
          acc[mfi][nf] = __builtin_amdgcn_mfma_f32_16x16x32_bf16(            \
              a[mfi], b[nf], acc[mfi][nf], 0, 0, 0);                         \
    }                                                                        \
  }                                                                          \
  __builtin_amdgcn_s_setprio(0);

  PREFETCH(1)
  COMPUTE(0)
  __syncthreads();
  BWRITE()
  __syncthreads();
  PREFETCH(2)
  COMPUTE(1)
  __syncthreads();
  BWRITE()
  __syncthreads();
  COMPUTE(2)

  // ---- epilogue: f = f0+nf*16+lr, w = m0+mfi*16+lg*4+r4; nf-inner stores.
  float bi[4];
#pragma unroll
  for (int nf = 0; nf < 4; ++nf) bi[nf] = bias[f0 + nf * 16 + lr];
  int ho = h0 + ro;
  long long ob = ((long long)(n * HH + ho)) * WWID * F_OUT + f0 + lr;
#pragma unroll
  for (int mfi = 0; mfi < 4; ++mfi) {
#pragma unroll
    for (int r4 = 0; r4 < 4; ++r4) {
      int w = m0 + mfi * 16 + lg * 4 + r4;
      float* op = out + ob + (long long)w * F_OUT;
#pragma unroll
      for (int nf = 0; nf < 4; ++nf)
        op[nf * 16] = fmaxf(acc[mfi][nf][r4] + bi[nf], 0.f);
    }
  }
#undef PREFETCH
#undef BWRITE
#undef COMPUTE
}

extern "C" void kernel_launch(void* const* d_in, const int* in_sizes, int n_in,
                              void* d_out, int out_size, void* d_ws, size_t ws_size,
                              hipStream_t stream) {
  const float* x    = (const float*)d_in[0];  // (16,128,128,64)
  const float* kern = (const float*)d_in[1];  // (3,3,64,128)
  const float* bias = (const float*)d_in[2];  // (128,)
  const float* D    = (const float*)d_in[3];  // (3,3,64,128)
  const float* gu   = (const float*)d_in[4];  // (1,128,64,9)

  unsigned short* AWsw = (unsigned short*)d_ws;  // 3 slices x 48 KiB = 144 KiB

  compute_aw<<<(F_OUT * C_IN + 255) / 256, 256, 0, stream>>>(kern, D, gu, AWsw);

  conv6<<<NB * (HH / 4), 1024, 0, stream>>>(x, AWsw, bias, (float*)d_out);
}